// Round 17
// baseline (49.682 us; speedup 1.0000x reference)
//
#include <hip/hip_runtime.h>
#include <hip/hip_bf16.h>
#include <cstdint>
#include <cstddef>

// Problem constants
#define NROWS 4096
#define DIMK  640
// reg = 1/LAMBDA = 10;  K = exp(-D/reg) = exp(0.2*S - 0.2), S = cosine sim
// K in [exp(-0.4), 1] -> affine uint8 quantization K ~= QA*q + QB
#define QB 0.67032004603564f           /* exp(-0.4) */
#define QA 0.0012928625645661f         /* (1 - exp(-0.4)) / 255 */
// Sinkhorn closed form:  v1_j = N / rowsumK_j ,  u1_i = c0 * v1_i ,
// c0 = 1/sum(v1);  W = c0 * v1_i * v1_j * K_ij , diag = 1.   [verified R8-R16]
// R17 = R16 + ONE change: GEMM tile decode is bx-major + XCD-chunked
// (1056 = 8*132) so each XCD's 132 blocks share consecutive B panels (T1).

typedef __bf16 bf16_t;
typedef __bf16 bf16x8 __attribute__((ext_vector_type(8)));
typedef float  f32x4  __attribute__((ext_vector_type(4)));

__device__ __forceinline__ int bytesum(uint32_t d) {
    return (int)(d & 255u) + (int)((d >> 8) & 255u) +
           (int)((d >> 16) & 255u) + (int)(d >> 24);
}

// ---------------------------------------------------------------------------
// Row-normalize x -> bf16 V; also zeroes rowsum (blocks 0..15).
// ---------------------------------------------------------------------------
__global__ __launch_bounds__(256)
void rownorm_kernel(const float* __restrict__ x, bf16_t* __restrict__ Vb,
                    unsigned int* __restrict__ rowsum) {
    const int t    = threadIdx.x;
    const int lane = t & 63;
    const int w    = t >> 6;
    if (blockIdx.x < 16) rowsum[blockIdx.x * 256 + t] = 0u;
    const int row = blockIdx.x * 4 + w;
    const float* xr = x + (size_t)row * DIMK;
    float xv[10];
    float ss = 0.f;
#pragma unroll
    for (int i = 0; i < 10; ++i) { xv[i] = xr[lane + i * 64]; ss += xv[i] * xv[i]; }
#pragma unroll
    for (int off = 32; off > 0; off >>= 1) ss += __shfl_xor(ss, off, 64);
    const float inv = 1.0f / sqrtf(ss);
    bf16_t* vr = Vb + (size_t)row * DIMK;
#pragma unroll
    for (int i = 0; i < 10; ++i) vr[lane + i * 64] = (bf16_t)(xv[i] * inv);
}

__global__ void init_u_kernel(float* __restrict__ u) {   // fallback path only
    const int i = blockIdx.x * 256 + threadIdx.x;
    if (i < NROWS) u[i] = 1.0f / (float)NROWS;
}

// ---------------------------------------------------------------------------
// helper: async global->LDS, 16B per lane
// ---------------------------------------------------------------------------
__device__ __forceinline__ void gload_lds16(const bf16_t* g, bf16_t* l) {
    __builtin_amdgcn_global_load_lds(
        (const __attribute__((address_space(1))) void*)g,
        (__attribute__((address_space(3))) void*)l,
        16, 0, 0);
}

// ---------------------------------------------------------------------------
// Symmetric K-GEMM (R16 structure, proven 49.3us total): 64x128 HALF-tiles
// (1056 blocks), LDS 48KB dbuf (3 blocks/CU), T3 2-phase per K-step.
// R17 single change: bx-major + XCD-chunk tile decode (T1 L2 locality).
// ---------------------------------------------------------------------------
__global__ __launch_bounds__(256, 3)
void gemm_k_sym_kernel(const bf16_t* __restrict__ Vb, unsigned char* __restrict__ Kq,
                       unsigned int* __restrict__ rowsum) {
    // dbuf layout (bf16 elems): buf*12288 -> A(4096) | B(8192)
    __shared__ __align__(16) bf16_t SMEM[2 * 12288];   // 48 KB

    const int t    = threadIdx.x;
    const int lane = t & 63;
    const int wid  = t >> 6;
    const int wr   = wid >> 1;       // 0..1 : 32-row band
    const int wc   = wid & 1;        // 0..1 : 64-col band
    const int lane15 = lane & 15;
    const int lhi    = lane >> 4;

    // R17: bijective XCD-chunk (1056 = 8*132) then bx-major triangular decode.
    // XCD k receives lids [132k, 132k+132): 66 consecutive prs -> shared B
    // panels stay L2-resident on that XCD.
    const int lid  = (blockIdx.x & 7) * 132 + (blockIdx.x >> 3);
    const int half = lid & 1;
    int tt = lid >> 1;               // pr in bx-major order: pr = bx(bx+1)/2 + by
    int bx = 0;
    while (tt > bx) { tt -= bx + 1; ++bx; }
    const int by = tt;
    const int rowAh = by * 128 + half * 64;   // this block's 64 A-rows
    const int rowB0 = bx * 128;

    f32x4 acc[2][4];
#pragma unroll
    for (int i = 0; i < 2; ++i)
#pragma unroll
        for (int j = 0; j < 4; ++j) acc[i][j] = (f32x4){0.f, 0.f, 0.f, 0.f};

#define STAGE_KT(buf, kt)                                                          \
    {                                                                              \
        bf16_t* Abuf = SMEM + (size_t)(buf) * 12288;                               \
        bf16_t* Bbuf = Abuf + 4096;                                                \
        _Pragma("unroll")                                                          \
        for (int it = 0; it < 2; ++it) {        /* A: 64 rows, 512 chunks */       \
            const int s = it * 256 + t;                                            \
            const int r = s >> 3;                                                  \
            const int c = (s & 7) ^ (r & 7);                                       \
            gload_lds16(Vb + (size_t)(rowAh + r) * DIMK + (kt) * 64 + c * 8,       \
                        Abuf + s * 8);                                             \
        }                                                                          \
        _Pragma("unroll")                                                          \
        for (int it = 0; it < 4; ++it) {        /* B: 128 rows, 1024 chunks */     \
            const int s = it * 256 + t;                                            \
            const int r = s >> 3;                                                  \
            const int c = (s & 7) ^ (r & 7);                                       \
            gload_lds16(Vb + (size_t)(rowB0 + r) * DIMK + (kt) * 64 + c * 8,       \
                        Bbuf + s * 8);                                             \
        }                                                                          \
    }

    STAGE_KT(0, 0);
    __syncthreads();   // drain: buffer 0 ready

    for (int kt = 0; kt < DIMK / 64; ++kt) {
        const int cur = kt & 1;
        if (kt < DIMK / 64 - 1) STAGE_KT(cur ^ 1, kt + 1);   // async prefetch

        const bf16_t* Ac = SMEM + (size_t)cur * 12288;
        const bf16_t* Bc = Ac + 4096;
#pragma unroll
        for (int kk = 0; kk < 2; ++kk) {
            bf16x8 af[2], bfr[4];
            const int cs = kk * 4 + lhi;
#pragma unroll
            for (int mi = 0; mi < 2; ++mi) {
                const int rl = wr * 32 + mi * 16 + lane15;      // 0..63
                af[mi] = *(const bf16x8*)(Ac + rl * 64 + ((cs ^ (rl & 7)) * 8));
            }
#pragma unroll
            for (int ni = 0; ni < 4; ++ni) {
                const int cl = wc * 64 + ni * 16 + lane15;      // 0..127
                bfr[ni] = *(const bf16x8*)(Bc + cl * 64 + ((cs ^ (cl & 7)) * 8));
            }
#pragma unroll
            for (int mi = 0; mi < 2; ++mi)
#pragma unroll
                for (int ni = 0; ni < 4; ++ni)
                    acc[mi][ni] = __builtin_amdgcn_mfma_f32_16x16x32_bf16(
                        af[mi], bfr[ni], acc[mi][ni], 0, 0, 0);
        }

        asm volatile("s_waitcnt vmcnt(0)" ::: "memory");
        __builtin_amdgcn_s_barrier();
        __builtin_amdgcn_sched_barrier(0);
    }
#undef STAGE_KT

    // ---- epilogue: quantize into transposed LDS tile Tt[c][r'] (u8, 8 KB)
    // dword d = r'>>2 (0..15), stored at Tt32[c*16 + (d ^ ((c&7)<<1))]
    uint32_t* Tt32 = (uint32_t*)SMEM;
    unsigned char* Tt = (unsigned char*)SMEM;
    __syncthreads();   // main-loop buffers dead; reuse base
#pragma unroll
    for (int mi = 0; mi < 2; ++mi) {
#pragma unroll
        for (int ni = 0; ni < 4; ++ni) {
            const int lr0 = wr * 32 + mi * 16 + lhi * 4;   // local row base (0..60)
            const int lc  = wc * 64 + ni * 16 + lane15;    // local col (0..127)
            uint32_t pack = 0;
#pragma unroll
            for (int j = 0; j < 4; ++j) {
                const float s = acc[mi][ni][j];
                float kv = __expf(0.2f * s - 0.2f);
                int q = (int)rintf((kv - QB) / QA);
                q = q < 0 ? 0 : (q > 255 ? 255 : q);
                if (rowAh + lr0 + j == rowB0 + lc) q = 0;
                pack |= (uint32_t)q << (8 * j);
            }
            const int d = lr0 >> 2;
            Tt32[lc * 16 + (d ^ ((lc & 7) << 1))] = pack;
        }
    }
    __syncthreads();

    // orientation 1 (always): K[rowB0+c][rowAh + ...], 64B per c-row.
    // 2 threads per c-row; + rowsum[rowB0+c] partial (this block's 64 rows).
    {
        const int c  = t >> 1;        // 0..127
        const int h8 = (t & 1) * 8;   // dword half
        uint32_t w[8];
        int bsum = 0;
#pragma unroll
        for (int k = 0; k < 8; ++k) {
            const int d = h8 + k;
            w[k] = Tt32[c * 16 + (d ^ ((c & 7) << 1))];
            bsum += bytesum(w[k]);
        }
        uint32_t* dst = (uint32_t*)(Kq + (size_t)(rowB0 + c) * NROWS + rowAh + h8 * 4);
#pragma unroll
        for (int k = 0; k < 2; ++k)
            ((uint4*)dst)[k] = make_uint4(w[4 * k], w[4 * k + 1], w[4 * k + 2], w[4 * k + 3]);
        bsum += __shfl_xor(bsum, 1, 64);
        if ((t & 1) == 0) atomicAdd(rowsum + rowB0 + c, (unsigned int)bsum);
    }

    // orientation 2 (off-diag only): K[rowAh+r][rowB0 + ...], 32B per thread
    // (4 threads per r-row); + rowsum[rowAh+r] partial (128 cols).
    if (bx != by) {
        const int r   = t >> 2;        // 0..63
        const int qtr = t & 3;         // which 32-col quarter
        const int d0  = r >> 2, b0 = r & 3;
        uint32_t* dst = (uint32_t*)(Kq + (size_t)(rowAh + r) * NROWS + rowB0 + qtr * 32);
        int bsum = 0;
#pragma unroll
        for (int k = 0; k < 8; ++k) {
            uint32_t pack = 0;
#pragma unroll
            for (int b = 0; b < 4; ++b) {
                const int c = qtr * 32 + k * 4 + b;
                pack |= (uint32_t)Tt[(c * 16 + (d0 ^ ((c & 7) << 1))) * 4 + b0] << (8 * b);
            }
            dst[k] = pack;
            bsum += bytesum(pack);
        }
        bsum += __shfl_xor(bsum, 1, 64);
        bsum += __shfl_xor(bsum, 2, 64);
        if (qtr == 0) atomicAdd(rowsum + rowAh + r, (unsigned int)bsum);
    }
}

// ---------------------------------------------------------------------------
// Closed-form final W (verified R8-R16):
//   v1[j] = N / (QA*rowsum[j] + 4095*QB) ; c0 = 1/sum(v1)
//   W[i][j] = (c0*v1[i]) * (QA*q[i][j] + QB) * v1[j] ; diag -> 1
// ---------------------------------------------------------------------------
__global__ __launch_bounds__(256)
void finalw_closed_kernel(const unsigned char* __restrict__ Kq,
                          const unsigned int* __restrict__ rowsum,
                          float* __restrict__ W) {
    __shared__ float xs[NROWS];
    __shared__ float sxp[4];
    const int t    = threadIdx.x;
    const int lane = t & 63;
    const int w    = t >> 6;

    float psum = 0.f;
    float4* xs4 = (float4*)xs;
    const uint4* rs4 = (const uint4*)rowsum;
#pragma unroll
    for (int i = 0; i < 4; ++i) {
        const uint4 rs = rs4[i * 256 + t];
        float4 vv;
        vv.x = (float)NROWS / fmaf(QA, (float)rs.x, 4095.0f * QB);
        vv.y = (float)NROWS / fmaf(QA, (float)rs.y, 4095.0f * QB);
        vv.z = (float)NROWS / fmaf(QA, (float)rs.z, 4095.0f * QB);
        vv.w = (float)NROWS / fmaf(QA, (float)rs.w, 4095.0f * QB);
        xs4[i * 256 + t] = vv;
        psum += vv.x + vv.y + vv.z + vv.w;
    }
#pragma unroll
    for (int off = 32; off > 0; off >>= 1) psum += __shfl_xor(psum, off, 64);
    if (lane == 0) sxp[w] = psum;
    __syncthreads();
    const float c0 = 1.0f / (sxp[0] + sxp[1] + sxp[2] + sxp[3]);

#pragma unroll
    for (int r = 0; r < 4; ++r) {
        const int grow = blockIdx.x * 4 + r;
        const float ui   = c0 * xs[grow];
        const float qa_u = QA * ui;
        const float qb_u = QB * ui;
        const uint32_t* Krow = (const uint32_t*)(Kq + (size_t)grow * NROWS);
        f32x4* Wrow = (f32x4*)(W + (size_t)grow * NROWS);
#pragma unroll
        for (int i = 0; i < 4; ++i) {
            const int idx = i * 256 + t;
            const uint32_t q = Krow[idx];
            const float4 vv = ((const float4*)xs4)[idx];
            f32x4 wv;
            wv[0] = fmaf(qa_u, (float)(q & 255u),         qb_u) * vv.x;
            wv[1] = fmaf(qa_u, (float)((q >> 8) & 255u),  qb_u) * vv.y;
            wv[2] = fmaf(qa_u, (float)((q >> 16) & 255u), qb_u) * vv.z;
            wv[3] = fmaf(qa_u, (float)(q >> 24),          qb_u) * vv.w;
            const int d = grow - idx * 4;
            if (d == 0) wv[0] = 1.0f;
            if (d == 1) wv[1] = 1.0f;
            if (d == 2) wv[2] = 1.0f;
            if (d == 3) wv[3] = 1.0f;
            __builtin_nontemporal_store(wv, Wrow + idx);
        }
    }
}

// ---------------------------------------------------------------------------
// f32 fallback path (only if ws too small for u8 K) — R5 semantics.
// ---------------------------------------------------------------------------
template <typename OUT_T>
__global__ __launch_bounds__(256)
void gemm_k_kernel(const bf16_t* __restrict__ Vb, OUT_T* __restrict__ Kout) {
    __shared__ __align__(16) bf16_t As[128 * 64];
    __shared__ __align__(16) bf16_t Bs[128 * 64];
    const int t    = threadIdx.x;
    const int lane = t & 63;
    const int wid  = t >> 6;
    const int wr   = wid >> 1;
    const int wc   = wid & 1;
    const int rowA0 = blockIdx.y * 128;
    const int rowB0 = blockIdx.x * 128;
    f32x4 acc[4][4];
#pragma unroll
    for (int i = 0; i < 4; ++i)
#pragma unroll
        for (int j = 0; j < 4; ++j) acc[i][j] = (f32x4){0.f, 0.f, 0.f, 0.f};
    for (int kt = 0; kt < DIMK / 64; ++kt) {
#pragma unroll
        for (int it = 0; it < 4; ++it) {
            const int s = it * 256 + t;
            const int r = s >> 3;
            const int c = (s & 7) ^ (r & 7);
            gload_lds16(Vb + (size_t)(rowA0 + r) * DIMK + kt * 64 + c * 8, As + s * 8);
            gload_lds16(Vb + (size_t)(rowB0 + r) * DIMK + kt * 64 + c * 8, Bs + s * 8);
        }
        __syncthreads();
#pragma unroll
        for (int kk = 0; kk < 2; ++kk) {
            bf16x8 af[4], bfr[4];
#pragma unroll
            for (int mi = 0; mi < 4; ++mi) {
                const int rl = wr * 64 + mi * 16 + (lane & 15);
                const int cs = kk * 4 + (lane >> 4);
                af[mi] = *(const bf16x8*)(As + rl * 64 + ((cs ^ (rl & 7)) * 8));
                const int cl = wc * 64 + mi * 16 + (lane & 15);
                bfr[mi] = *(const bf16x8*)(Bs + cl * 64 + ((cs ^ (cl & 7)) * 8));
            }
#pragma unroll
            for (int mi = 0; mi < 4; ++mi)
#pragma unroll
                for (int ni = 0; ni < 4; ++ni)
                    acc[mi][ni] = __builtin_amdgcn_mfma_f32_16x16x32_bf16(
                        af[mi], bfr[ni], acc[mi][ni], 0, 0, 0);
        }
        __syncthreads();
    }
#pragma unroll
    for (int mi = 0; mi < 4; ++mi)
#pragma unroll
        for (int ni = 0; ni < 4; ++ni)
#pragma unroll
            for (int j = 0; j < 4; ++j) {
                const int grow = rowA0 + wr * 64 + mi * 16 + (lane >> 4) * 4 + j;
                const int gcol = rowB0 + wc * 64 + ni * 16 + (lane & 15);
                float kv = __expf(0.2f * acc[mi][ni][j] - 0.2f);
                if (grow == gcol) kv = 0.0f;
                Kout[(size_t)grow * NROWS + gcol] = (OUT_T)kv;
            }
}

__global__ void matvec_f32_kernel(const float* __restrict__ K,
                                  const float* __restrict__ x,
                                  float* __restrict__ y) {
    const int row = blockIdx.x;
    const int t   = threadIdx.x;
    const float4* Kr = (const float4*)(K + (size_t)row * NROWS);
    const float4* xv = (const float4*)x;
    float s = 0.f;
#pragma unroll
    for (int i = 0; i < 4; ++i) {
        const int idx = i * 256 + t;
        const float4 kv = Kr[idx];
        const float4 xw = xv[idx];
        s += kv.x * xw.x + kv.y * xw.y + kv.z * xw.z + kv.w * xw.w;
    }
    for (int off = 32; off > 0; off >>= 1) s += __shfl_down(s, off, 64);
    __shared__ float p[4];
    const int lane = t & 63, wid = t >> 6;
    if (lane == 0) p[wid] = s;
    __syncthreads();
    if (t == 0) y[row] = 1.0f / (p[0] + p[1] + p[2] + p[3]);
}

__global__ void finalw_f32_kernel(float* __restrict__ W,
                                  const float* __restrict__ u,
                                  const float* __restrict__ v) {
    const size_t idx  = (size_t)blockIdx.x * 256 + threadIdx.x;
    const size_t base = idx * 4;
    const int i  = (int)(base >> 12);
    const int j0 = (int)(base & 4095);
    const float ui = u[i];
    float4 kv = ((const float4*)W)[idx];
    const float4 vv = *(const float4*)(v + j0);
    float4 w;
    w.x = ui * kv.x * vv.x;
    w.y = ui * kv.y * vv.y;
    w.z = ui * kv.z * vv.z;
    w.w = ui * kv.w * vv.w;
    const int d = i - j0;
    if (d == 0) w.x = 1.0f;
    if (d == 1) w.y = 1.0f;
    if (d == 2) w.z = 1.0f;
    if (d == 3) w.w = 1.0f;
    ((float4*)W)[idx] = w;
}

// ---------------------------------------------------------------------------
extern "C" void kernel_launch(void* const* d_in, const int* in_sizes, int n_in,
                              void* d_out, int out_size, void* d_ws, size_t ws_size,
                              hipStream_t stream) {
    const float* x = (const float*)d_in[0];
    float* W = (float*)d_out;
    char* ws = (char*)d_ws;

    size_t off = 0;
    bf16_t* Vb = (bf16_t*)(ws + off); off += (size_t)NROWS * DIMK * sizeof(bf16_t);
    unsigned int* rowsum = (unsigned int*)(ws + off); off += (size_t)NROWS * sizeof(unsigned int);
    float*  u  = (float*)(ws + off);  off += (size_t)NROWS * sizeof(float);
    float*  v  = (float*)(ws + off);  off += (size_t)NROWS * sizeof(float);
    off = (off + 255) & ~(size_t)255;
    const size_t kq_bytes = (size_t)NROWS * NROWS;
    const bool use_u8K = (ws_size >= off + kq_bytes);
    unsigned char* Kq = (unsigned char*)(ws + off);

    if (use_u8K) {
        rownorm_kernel<<<NROWS / 4, 256, 0, stream>>>(x, Vb, rowsum);
        gemm_k_sym_kernel<<<1056, 256, 0, stream>>>(Vb, Kq, rowsum);
        finalw_closed_kernel<<<NROWS / 4, 256, 0, stream>>>(Kq, rowsum, W);
    } else {
        rownorm_kernel<<<NROWS / 4, 256, 0, stream>>>(x, Vb, rowsum);
        init_u_kernel<<<NROWS / 256, 256, 0, stream>>>(u);
        dim3 ggrid(NROWS / 128, NROWS / 128);
        gemm_k_kernel<float><<<ggrid, 256, 0, stream>>>(Vb, W);
        for (int it = 0; it < 2; ++it) {
            matvec_f32_kernel<<<NROWS, 256, 0, stream>>>(W, u, v);
            matvec_f32_kernel<<<NROWS, 256, 0, stream>>>(W, v, u);
        }
        finalw_f32_kernel<<<(NROWS * (NROWS / 4)) / 256, 256, 0, stream>>>(W, u, v);
    }
}